// Round 10
// baseline (206.899 us; speedup 1.0000x reference)
//
#include <hip/hip_runtime.h>
#include <cstdint>
#include <cstddef>

typedef __attribute__((ext_vector_type(8))) _Float16 f16x8;
typedef __attribute__((ext_vector_type(4))) _Float16 f16x4;
typedef __attribute__((ext_vector_type(4))) float f32x4;

#define MFMA_16x16x32(a, b, c) __builtin_amdgcn_mfma_f32_16x16x32_f16((a), (b), (c), 0, 0, 0)
#define MFMA_16x16x16(a, b, c) __builtin_amdgcn_mfma_f32_16x16x16f16((a), (b), (c), 0, 0, 0)

static constexpr int kB = 2, kS = 2048, kDim = 1024, kH = 16, kD = 64;
static constexpr int kM = kB * kS;  // 4096 rows total
// 1/sqrt(64) * log2(e), folded into Q at projection time
static constexpr float kQScale = 0.125f * 1.44269504088896340736f;
// -1e6 * log2(e): mask penalty in exp2 domain
static constexpr float kPenC = 1.44269504088896340736e6f;

// Raw workgroup barrier: drain only LDS ops (lgkmcnt), NOT vmcnt, so register
// prefetch loads stay in flight across the barrier.
__device__ __forceinline__ void wg_barrier_lds() {
  asm volatile("s_waitcnt lgkmcnt(0)" ::: "memory");
  __builtin_amdgcn_s_barrier();
}

// ---------------- elementwise f32 -> f16 ----------------
__global__ void cvt_f32_to_f16(const float* __restrict__ in, _Float16* __restrict__ out, int n8) {
  int i = blockIdx.x * blockDim.x + threadIdx.x;
  if (i >= n8) return;
  const float4* p = (const float4*)in + (size_t)i * 2;
  float4 a = p[0], b = p[1];
  f16x8 h;
  h[0] = (_Float16)a.x; h[1] = (_Float16)a.y; h[2] = (_Float16)a.z; h[3] = (_Float16)a.w;
  h[4] = (_Float16)b.x; h[5] = (_Float16)b.y; h[6] = (_Float16)b.z; h[7] = (_Float16)b.w;
  ((f16x8*)out)[i] = h;
}

// ------------- W [K][N] f32  ->  Wt [N][K] f16 (4 matrices) -------------
__global__ void transpose_cvt_w(const float* __restrict__ w0, const float* __restrict__ w1,
                                const float* __restrict__ w2, const float* __restrict__ w3,
                                _Float16* __restrict__ o0, _Float16* __restrict__ o1,
                                _Float16* __restrict__ o2, _Float16* __restrict__ o3) {
  const float* w; _Float16* o;
  switch (blockIdx.z) {
    case 0: w = w0; o = o0; break;
    case 1: w = w1; o = o1; break;
    case 2: w = w2; o = o2; break;
    default: w = w3; o = o3; break;
  }
  __shared__ alignas(16) _Float16 tile[64][72];
  const int kt = blockIdx.x * 64;
  const int nt = blockIdx.y * 64;
  const int tr = threadIdx.x >> 4;
  const int tc = threadIdx.x & 15;
#pragma unroll
  for (int rr = 0; rr < 4; ++rr) {
    int r = rr * 16 + tr;
    float4 v = *(const float4*)&w[(size_t)(kt + r) * kDim + nt + tc * 4];
    f16x4 hv;
    hv[0] = (_Float16)v.x; hv[1] = (_Float16)v.y; hv[2] = (_Float16)v.z; hv[3] = (_Float16)v.w;
    *(f16x4*)&tile[r][tc * 4] = hv;
  }
  __syncthreads();
#pragma unroll
  for (int rr = 0; rr < 4; ++rr) {
    int nl = rr * 16 + tr;
    f16x4 hv;
    hv[0] = tile[tc * 4 + 0][nl];
    hv[1] = tile[tc * 4 + 1][nl];
    hv[2] = tile[tc * 4 + 2][nl];
    hv[3] = tile[tc * 4 + 3][nl];
    *(f16x4*)&o[(size_t)(nt + nl) * kDim + kt + tc * 4] = hv;
  }
}

// ------------- QKV projection GEMM (BK=64, double-buffered LDS, 1 barrier/iter)
// R9 post-mortem: BK=32/3-blocks-per-CU REGRESSED (+7us): 2x barriers, half
// the MFMA per phase. Reverted to the R7-measured BK=64 form.
__global__ __launch_bounds__(256, 2) void gemm_qkv(
    const _Float16* __restrict__ A,
    const _Float16* __restrict__ wt0, const _Float16* __restrict__ wt1, const _Float16* __restrict__ wt2,
    const float* __restrict__ bias0, const float* __restrict__ bias1, const float* __restrict__ bias2,
    _Float16* __restrict__ oq, _Float16* __restrict__ ok, _Float16* __restrict__ ov) {
  const _Float16* Bt; const float* bias; _Float16* out;
  switch (blockIdx.z) {
    case 0: Bt = wt0; bias = bias0; out = oq; break;
    case 1: Bt = wt1; bias = bias1; out = ok; break;
    default: Bt = wt2; bias = bias2; out = ov; break;
  }
  __shared__ alignas(16) _Float16 As[2][128 * 72];
  __shared__ alignas(16) _Float16 Bs[2][128 * 72];
  const int tid = threadIdx.x;
  const int lane = tid & 63;
  const int wave = tid >> 6;
  const int wm = wave & 1, wn = wave >> 1;
  const int l15 = lane & 15, quad = lane >> 4;
  const int m0 = blockIdx.x * 128, n0 = blockIdx.y * 128;

  const int srow = tid >> 3;             // staging row (tid + 256*i -> row = srow + 32*i)
  const int skc = (tid & 7) * 8;         // staging k-offset

  f32x4 acc[4][4] = {};
  f16x8 ra[4], rb[4];

#pragma unroll
  for (int i = 0; i < 4; ++i) {
    int row = srow + 32 * i;
    ra[i] = *(const f16x8*)&A[(size_t)(m0 + row) * kDim + skc];
    rb[i] = *(const f16x8*)&Bt[(size_t)(n0 + row) * kDim + skc];
  }
#pragma unroll
  for (int i = 0; i < 4; ++i) {
    int row = srow + 32 * i;
    *(f16x8*)&As[0][row * 72 + skc] = ra[i];
    *(f16x8*)&Bs[0][row * 72 + skc] = rb[i];
  }

  for (int kt = 0; kt < 16; ++kt) {
    const int cur = kt & 1;
    if (kt + 1 < 16) {
      int k0 = (kt + 1) * 64;
#pragma unroll
      for (int i = 0; i < 4; ++i) {
        int row = srow + 32 * i;
        ra[i] = *(const f16x8*)&A[(size_t)(m0 + row) * kDim + k0 + skc];
        rb[i] = *(const f16x8*)&Bt[(size_t)(n0 + row) * kDim + k0 + skc];
      }
    }
    wg_barrier_lds();  // writes to buffer `cur` (prev iter / prologue) complete
#pragma unroll
    for (int kk = 0; kk < 2; ++kk) {
      f16x8 af[4], bf[4];
#pragma unroll
      for (int t = 0; t < 4; ++t) af[t] = *(const f16x8*)&As[cur][(wm * 64 + t * 16 + l15) * 72 + kk * 32 + quad * 8];
#pragma unroll
      for (int t = 0; t < 4; ++t) bf[t] = *(const f16x8*)&Bs[cur][(wn * 64 + t * 16 + l15) * 72 + kk * 32 + quad * 8];
      __builtin_amdgcn_s_setprio(1);
#pragma unroll
      for (int i = 0; i < 4; ++i)
#pragma unroll
        for (int j = 0; j < 4; ++j)
          acc[i][j] = MFMA_16x16x32(af[i], bf[j], acc[i][j]);
      __builtin_amdgcn_s_setprio(0);
    }
    if (kt + 1 < 16) {
#pragma unroll
      for (int i = 0; i < 4; ++i) {
        int row = srow + 32 * i;
        *(f16x8*)&As[cur ^ 1][row * 72 + skc] = ra[i];
        *(f16x8*)&Bs[cur ^ 1][row * 72 + skc] = rb[i];
      }
    }
  }

  const int mbase = m0 + wm * 64 + quad * 4;
  const int nbase = n0 + wn * 64 + l15;
  if (blockIdx.z == 2) {
#pragma unroll
    for (int j = 0; j < 4; ++j) {
      int n = nbase + j * 16;
      float bv = bias[n];
      int h = n >> 6, d = n & 63;
#pragma unroll
      for (int i = 0; i < 4; ++i) {
        int m = mbase + i * 16;
        int b = m >> 11, s = m & (kS - 1);
        f16x4 hv;
#pragma unroll
        for (int r = 0; r < 4; ++r) hv[r] = (_Float16)(acc[i][j][r] + bv);
        *(f16x4*)&out[((size_t)((b * kH + h) * kD + d)) * kS + s] = hv;
      }
    }
  } else {
    const float osc = (blockIdx.z == 0) ? kQScale : 1.0f;
#pragma unroll
    for (int j = 0; j < 4; ++j) {
      int n = nbase + j * 16;
      float bv = bias[n];
      int h = n >> 6, d = n & 63;
#pragma unroll
      for (int i = 0; i < 4; ++i) {
        int mrow = mbase + i * 16;
#pragma unroll
        for (int r = 0; r < 4; ++r) {
          int m = mrow + r;
          int b = m >> 11, s = m & (kS - 1);
          out[(size_t)(((b * kH + h) * kS) + s) * kD + d] = (_Float16)((acc[i][j][r] + bv) * osc);
        }
      }
    }
  }
}

// ------------- flash attention v8: key-parallel wave groups -------------
// R9 post-mortem: occupancy (18.6%) is PROBLEM-SIZE-forced: at 32 q/wave the
// problem supplies exactly 2048 waves = 2/SIMD. Shrinking q/wave doubles LDS
// traffic per FLOP (R5 regression). v8 doubles TLP without touching per-wave
// q: 512-thread blocks, 8 waves = 4 q-strips x 2 KEY-groups. Group g handles
// key tiles of parity g (its own LDS buffer, no buffer flip). This softmax has
// no running max (pure exp2+penalty sums), so partial (O,l) merge = ADDITION:
// one LDS exchange at the end. 80KB LDS -> 2 blocks/CU = 16 waves/CU =
// 4 waves/SIMD (2x R9). Barrier count unchanged (16). Per-wave LDS-per-FLOP
// unchanged. Keep: P-in-regs, pen C-init, reg prefetch, lgkm barriers, swizzle.
__global__ __launch_bounds__(512, 4) void attn(
    const _Float16* __restrict__ Q, const _Float16* __restrict__ K,
    const _Float16* __restrict__ V, const float* __restrict__ mask,
    _Float16* __restrict__ ctx) {
  // 512 blocks, 8 XCDs -> 64 logical/XCD = 4 consecutive bh (2MB K/V <= 4MB L2)
  const int id = blockIdx.x;
  const int logical = (id & 7) * 64 + (id >> 3);
  const int bh = logical >> 4;    // 0..31
  const int qblk = logical & 15;  // 0..15
  const int b = bh >> 4;
  const int q0 = qblk * 128;
  const int tid = threadIdx.x, lane = tid & 63, wave = tid >> 6;
  const int strip = wave & 3;     // q-strip (32 q each)
  const int kgrp = wave >> 2;     // key-tile parity group
  const int l15 = lane & 15, quad = lane >> 4;

  __shared__ alignas(16) _Float16 Ks[2][128 * 72];  // [grp][key][d], stride 144B
  __shared__ alignas(16) _Float16 Vs[2][64 * 136];  // [grp][d][key], stride 272B
  __shared__ alignas(16) float pens[kS];            // (mask-1)*kPenC for all keys

  const _Float16* Qh = Q + (size_t)bh * kS * kD;
  const _Float16* Kh = K + (size_t)bh * kS * kD;
  const _Float16* Vh = V + (size_t)bh * kS * kD;  // [d][s]

  // mask penalties for the whole row, staged once (8KB, 512 thr x float4)
  {
    float4 mv4 = *(const float4*)&mask[(size_t)b * kS + tid * 4];
    float4 pv;
    pv.x = (mv4.x - 1.0f) * kPenC;
    pv.y = (mv4.y - 1.0f) * kPenC;
    pv.z = (mv4.z - 1.0f) * kPenC;
    pv.w = (mv4.w - 1.0f) * kPenC;
    *(float4*)&pens[tid * 4] = pv;
  }

  // Q for this wave's 2 strips of 16 rows, in registers
  f16x8 qf[2][2];
#pragma unroll
  for (int t = 0; t < 2; ++t) {
    int qrow = q0 + strip * 32 + t * 16 + l15;
#pragma unroll
    for (int kk = 0; kk < 2; ++kk)
      qf[t][kk] = *(const f16x8*)&Qh[(size_t)qrow * kD + kk * 32 + quad * 8];
  }

  f16x4 ones4;
#pragma unroll
  for (int i = 0; i < 4; ++i) ones4[i] = (_Float16)1.0f;

  f32x4 o_acc[2][4] = {};  // O[q][d]: lane holds q=quad*4+r, d=c*16+l15
  f32x4 l_acc[2] = {};     // l[q=quad*4+r]

  // staging: 512 threads cover BOTH 128-key tiles of a 256-key superiter
  const int skc = (tid & 7) * 8;    // K col offset (8 thr/row)
  const int vcol = (tid & 15) * 8;  // V col offset (16 thr/row)

  // prologue: load superiter 0 (keys 0..255) into regs, stage into bufs
  f16x8 kreg[4], vreg[4];
#pragma unroll
  for (int i = 0; i < 4; ++i) {
    int rr = (tid >> 3) + 64 * i;          // 0..255 over both tiles
    kreg[i] = *(const f16x8*)&Kh[(size_t)rr * kD + skc];
  }
#pragma unroll
  for (int i = 0; i < 4; ++i) {
    int vrr = (tid >> 4) + 32 * i;         // 0..127: tile=vrr>>6, d=vrr&63
    vreg[i] = *(const f16x8*)&Vh[(size_t)(vrr & 63) * kS + (vrr >> 6) * 128 + vcol];
  }
#pragma unroll
  for (int i = 0; i < 4; ++i) {
    int rr = (tid >> 3) + 64 * i;
    *(f16x8*)&Ks[rr >> 7][(rr & 127) * 72 + skc] = kreg[i];
  }
#pragma unroll
  for (int i = 0; i < 4; ++i) {
    int vrr = (tid >> 4) + 32 * i;
    *(f16x8*)&Vs[vrr >> 6][(vrr & 63) * 136 + vcol] = vreg[i];
  }

  for (int s = 0; s < 8; ++s) {
    wg_barrier_lds();  // staged writes (prev iter / prologue) visible; pens too
    if (s + 1 < 8) {   // issue next superiter's loads; fly under compute
      int nb = (s + 1) * 256;
#pragma unroll
      for (int i = 0; i < 4; ++i) {
        int rr = (tid >> 3) + 64 * i;
        kreg[i] = *(const f16x8*)&Kh[(size_t)(nb + rr) * kD + skc];
      }
#pragma unroll
      for (int i = 0; i < 4; ++i) {
        int vrr = (tid >> 4) + 32 * i;
        vreg[i] = *(const f16x8*)&Vh[(size_t)(vrr & 63) * kS + nb + (vrr >> 6) * 128 + vcol];
      }
    }

    const int kb = s * 256 + kgrp * 128;   // this group's 128-key tile
#pragma unroll
    for (int colt = 0; colt < 8; ++colt) {
      f32x4 pn = *(const f32x4*)&pens[kb + colt * 16 + quad * 4];
      f16x8 kf0 = *(const f16x8*)&Ks[kgrp][(colt * 16 + l15) * 72 + quad * 8];
      f16x8 kf1 = *(const f16x8*)&Ks[kgrp][(colt * 16 + l15) * 72 + 32 + quad * 8];
      f32x4 s0 = pn, s1 = pn;
      s0 = MFMA_16x16x32(kf0, qf[0][0], s0);
      s0 = MFMA_16x16x32(kf1, qf[0][1], s0);
      s1 = MFMA_16x16x32(kf0, qf[1][0], s1);
      s1 = MFMA_16x16x32(kf1, qf[1][1], s1);
      f16x4 vf0 = *(const f16x4*)&Vs[kgrp][(0 * 16 + l15) * 136 + colt * 16 + quad * 4];
      f16x4 vf1 = *(const f16x4*)&Vs[kgrp][(1 * 16 + l15) * 136 + colt * 16 + quad * 4];
      f16x4 vf2 = *(const f16x4*)&Vs[kgrp][(2 * 16 + l15) * 136 + colt * 16 + quad * 4];
      f16x4 vf3 = *(const f16x4*)&Vs[kgrp][(3 * 16 + l15) * 136 + colt * 16 + quad * 4];
      f16x4 pa0, pa1;
#pragma unroll
      for (int r = 0; r < 4; ++r) {
        pa0[r] = (_Float16)__builtin_exp2f(s0[r]);
        pa1[r] = (_Float16)__builtin_exp2f(s1[r]);
      }
      __builtin_amdgcn_s_setprio(1);
      o_acc[0][0] = MFMA_16x16x16(pa0, vf0, o_acc[0][0]);
      o_acc[0][1] = MFMA_16x16x16(pa0, vf1, o_acc[0][1]);
      o_acc[0][2] = MFMA_16x16x16(pa0, vf2, o_acc[0][2]);
      o_acc[0][3] = MFMA_16x16x16(pa0, vf3, o_acc[0][3]);
      o_acc[1][0] = MFMA_16x16x16(pa1, vf0, o_acc[1][0]);
      o_acc[1][1] = MFMA_16x16x16(pa1, vf1, o_acc[1][1]);
      o_acc[1][2] = MFMA_16x16x16(pa1, vf2, o_acc[1][2]);
      o_acc[1][3] = MFMA_16x16x16(pa1, vf3, o_acc[1][3]);
      l_acc[0] = MFMA_16x16x16(pa0, ones4, l_acc[0]);
      l_acc[1] = MFMA_16x16x16(pa1, ones4, l_acc[1]);
      __builtin_amdgcn_s_setprio(0);
    }

    wg_barrier_lds();  // all waves done reading both buffers
    if (s + 1 < 8) {   // stage next superiter into the (now-free) buffers
#pragma unroll
      for (int i = 0; i < 4; ++i) {
        int rr = (tid >> 3) + 64 * i;
        *(f16x8*)&Ks[rr >> 7][(rr & 127) * 72 + skc] = kreg[i];
      }
#pragma unroll
      for (int i = 0; i < 4; ++i) {
        int vrr = (tid >> 4) + 32 * i;
        *(f16x8*)&Vs[vrr >> 6][(vrr & 63) * 136 + vcol] = vreg[i];
      }
    }
  }

  // merge: group 1 publishes partial (O,l) via LDS (reusing Ks/Vs space);
  // group 0 adds, normalizes, stores. Pure sums -> no rescale needed.
  f32x4* obuf = (f32x4*)&Ks[0][0];  // [strip][t][c][lane] = 4*2*4*64*16B = 32KB
  f32x4* lbuf = (f32x4*)&Vs[0][0];  // [strip][t][lane]    = 4*2*64*16B  = 8KB
  if (kgrp == 1) {
#pragma unroll
    for (int t = 0; t < 2; ++t) {
#pragma unroll
      for (int c = 0; c < 4; ++c)
        obuf[(((strip * 2 + t) * 4 + c) << 6) + lane] = o_acc[t][c];
      lbuf[((strip * 2 + t) << 6) + lane] = l_acc[t];
    }
  }
  wg_barrier_lds();
  if (kgrp == 0) {
    const int h = bh & 15;
#pragma unroll
    for (int t = 0; t < 2; ++t) {
      f32x4 lsum = l_acc[t] + lbuf[((strip * 2 + t) << 6) + lane];
      f32x4 linv;
#pragma unroll
      for (int r = 0; r < 4; ++r) linv[r] = 1.0f / lsum[r];
      int qbase = q0 + strip * 32 + t * 16 + quad * 4;
#pragma unroll
      for (int c = 0; c < 4; ++c) {
        f32x4 o = o_acc[t][c] + obuf[(((strip * 2 + t) * 4 + c) << 6) + lane];
#pragma unroll
        for (int r = 0; r < 4; ++r) {
          ctx[((size_t)(b * kS + qbase + r)) * kDim + h * kD + c * 16 + l15] =
              (_Float16)(o[r] * linv[r]);
        }
      }
    }
  }
}

// ------------- output GEMM (BM=64 for 512 blocks = 2/CU; BK=64, dbuf LDS) -------------
__global__ __launch_bounds__(256, 2) void gemm_out(
    const _Float16* __restrict__ A, const _Float16* __restrict__ Bt,
    const float* __restrict__ bias, float* __restrict__ out) {
  __shared__ alignas(16) _Float16 As[2][64 * 72];
  __shared__ alignas(16) _Float16 Bs[2][128 * 72];
  const int tid = threadIdx.x;
  const int lane = tid & 63;
  const int wave = tid >> 6;
  const int wm = wave & 1, wn = wave >> 1;   // 2x2 waves: 32M x 64N each
  const int l15 = lane & 15, quad = lane >> 4;
  const int m0 = blockIdx.x * 64, n0 = blockIdx.y * 128;

  const int srow = tid >> 3;
  const int skc = (tid & 7) * 8;

  f32x4 acc[2][4] = {};
  f16x8 ra[2], rb[4];

#pragma unroll
  for (int i = 0; i < 2; ++i)
    ra[i] = *(const f16x8*)&A[(size_t)(m0 + srow + 32 * i) * kDim + skc];
#pragma unroll
  for (int i = 0; i < 4; ++i)
    rb[i] = *(const f16x8*)&Bt[(size_t)(n0 + srow + 32 * i) * kDim + skc];
#pragma unroll
  for (int i = 0; i < 2; ++i)
    *(f16x8*)&As[0][(srow + 32 * i) * 72 + skc] = ra[i];
#pragma unroll
  for (int i = 0; i < 4; ++i)
    *(f16x8*)&Bs[0][(srow + 32 * i) * 72 + skc] = rb[i];

  for (int kt = 0; kt < 16; ++kt) {
    const int cur = kt & 1;
    if (kt + 1 < 16) {
      int k0 = (kt + 1) * 64;
#pragma unroll
      for (int i = 0; i < 2; ++i)
        ra[i] = *(const f16x8*)&A[(size_t)(m0 + srow + 32 * i) * kDim + k0 + skc];
#pragma unroll
      for (int i = 0; i < 4; ++i)
        rb[i] = *(const f16x8*)&Bt[(size_t)(n0 + srow + 32 * i) * kDim + k0 + skc];
    }
    wg_barrier_lds();
#pragma unroll
    for (int kk = 0; kk < 2; ++kk) {
      f16x8 af[2], bf[4];
#pragma unroll
      for (int t = 0; t < 2; ++t) af[t] = *(const f16x8*)&As[cur][(wm * 32 + t * 16 + l15) * 72 + kk * 32 + quad * 8];
#pragma unroll
      for (int t = 0; t < 4; ++t) bf[t] = *(const f16x8*)&Bs[cur][(wn * 64 + t * 16 + l15) * 72 + kk * 32 + quad * 8];
      __builtin_amdgcn_s_setprio(1);
#pragma unroll
      for (int i = 0; i < 2; ++i)
#pragma unroll
        for (int j = 0; j < 4; ++j)
          acc[i][j] = MFMA_16x16x32(af[i], bf[j], acc[i][j]);
      __builtin_amdgcn_s_setprio(0);
    }
    if (kt + 1 < 16) {
#pragma unroll
      for (int i = 0; i < 2; ++i)
        *(f16x8*)&As[cur ^ 1][(srow + 32 * i) * 72 + skc] = ra[i];
#pragma unroll
      for (int i = 0; i < 4; ++i)
        *(f16x8*)&Bs[cur ^ 1][(srow + 32 * i) * 72 + skc] = rb[i];
    }
  }

  const int mbase = m0 + wm * 32 + quad * 4;
  const int nbase = n0 + wn * 64 + l15;
#pragma unroll
  for (int j = 0; j < 4; ++j) {
    int n = nbase + j * 16;
    float bv = bias[n];
#pragma unroll
    for (int i = 0; i < 2; ++i) {
      int mrow = mbase + i * 16;
#pragma unroll
      for (int r = 0; r < 4; ++r)
        out[(size_t)(mrow + r) * kDim + n] = acc[i][j][r] + bv;
    }
  }
}

extern "C" void kernel_launch(void* const* d_in, const int* in_sizes, int n_in,
                              void* d_out, int out_size, void* d_ws, size_t ws_size,
                              hipStream_t stream) {
  (void)in_sizes; (void)n_in; (void)out_size; (void)ws_size;
  const float* X    = (const float*)d_in[0];
  const float* mask = (const float*)d_in[1];
  const float* Wq   = (const float*)d_in[2];
  const float* bq   = (const float*)d_in[3];
  const float* Wk   = (const float*)d_in[4];
  const float* bk   = (const float*)d_in[5];
  const float* Wv   = (const float*)d_in[6];
  const float* bv   = (const float*)d_in[7];
  const float* Wo   = (const float*)d_in[8];
  const float* bo   = (const float*)d_in[9];
  float* out = (float*)d_out;

  char* ws = (char*)d_ws;
  _Float16* Xh   = (_Float16*)(ws);                        // 8 MB
  _Float16* Wqt  = (_Float16*)(ws + ((size_t)8  << 20));   // 2 MB each
  _Float16* Wkt  = (_Float16*)(ws + ((size_t)10 << 20));
  _Float16* Wvt  = (_Float16*)(ws + ((size_t)12 << 20));
  _Float16* Wot  = (_Float16*)(ws + ((size_t)14 << 20));
  _Float16* Qh   = (_Float16*)(ws + ((size_t)16 << 20));   // 8 MB each
  _Float16* Kh   = (_Float16*)(ws + ((size_t)24 << 20));
  _Float16* Vh   = (_Float16*)(ws + ((size_t)32 << 20));   // [B][H][D][S]
  _Float16* Ch   = (_Float16*)(ws + ((size_t)40 << 20));   // 8 MB

  cvt_f32_to_f16<<<dim3(kM * kDim / 8 / 256), dim3(256), 0, stream>>>(X, Xh, kM * kDim / 8);
  transpose_cvt_w<<<dim3(16, 16, 4), dim3(256), 0, stream>>>(Wq, Wk, Wv, Wo, Wqt, Wkt, Wvt, Wot);
  gemm_qkv<<<dim3(32, 8, 3), dim3(256), 0, stream>>>(Xh, Wqt, Wkt, Wvt, bq, bk, bv, Qh, Kh, Vh);
  attn<<<dim3(512), dim3(512), 0, stream>>>(Qh, Kh, Vh, mask, Ch);
  gemm_out<<<dim3(64, 8), dim3(256), 0, stream>>>(Ch, Wot, bo, out);
}

// Round 11
// 204.821 us; speedup vs baseline: 1.0101x; 1.0101x over previous
//
#include <hip/hip_runtime.h>
#include <cstdint>
#include <cstddef>

typedef __attribute__((ext_vector_type(8))) _Float16 f16x8;
typedef __attribute__((ext_vector_type(4))) _Float16 f16x4;
typedef __attribute__((ext_vector_type(4))) float f32x4;

#define MFMA_16x16x32(a, b, c) __builtin_amdgcn_mfma_f32_16x16x32_f16((a), (b), (c), 0, 0, 0)
#define MFMA_16x16x16(a, b, c) __builtin_amdgcn_mfma_f32_16x16x16f16((a), (b), (c), 0, 0, 0)

static constexpr int kB = 2, kS = 2048, kDim = 1024, kH = 16, kD = 64;
static constexpr int kM = kB * kS;  // 4096 rows total
// 1/sqrt(64) * log2(e), folded into Q at projection time
static constexpr float kQScale = 0.125f * 1.44269504088896340736f;
// -1e6 * log2(e): mask penalty in exp2 domain
static constexpr float kPenC = 1.44269504088896340736e6f;

// Raw workgroup barrier: drain only LDS ops (lgkmcnt), NOT vmcnt.
__device__ __forceinline__ void wg_barrier_lds() {
  asm volatile("s_waitcnt lgkmcnt(0)" ::: "memory");
  __builtin_amdgcn_s_barrier();
}
// Full drain barrier for global_load_lds double-buffering (T3 2-phase recipe).
__device__ __forceinline__ void wg_barrier_vm() {
  asm volatile("s_waitcnt vmcnt(0) lgkmcnt(0)" ::: "memory");
  __builtin_amdgcn_s_barrier();
}
// Async global->LDS, 16B per lane: lane i's data lands at lptr + i*16.
__device__ __forceinline__ void gload16(const void* g, void* l) {
  __builtin_amdgcn_global_load_lds((const __attribute__((address_space(1))) void*)g,
                                   (__attribute__((address_space(3))) void*)l, 16, 0, 0);
}

// ---------------- elementwise f32 -> f16 ----------------
__global__ void cvt_f32_to_f16(const float* __restrict__ in, _Float16* __restrict__ out, int n8) {
  int i = blockIdx.x * blockDim.x + threadIdx.x;
  if (i >= n8) return;
  const float4* p = (const float4*)in + (size_t)i * 2;
  float4 a = p[0], b = p[1];
  f16x8 h;
  h[0] = (_Float16)a.x; h[1] = (_Float16)a.y; h[2] = (_Float16)a.z; h[3] = (_Float16)a.w;
  h[4] = (_Float16)b.x; h[5] = (_Float16)b.y; h[6] = (_Float16)b.z; h[7] = (_Float16)b.w;
  ((f16x8*)out)[i] = h;
}

// ------------- W [K][N] f32  ->  Wt [N][K] f16 (4 matrices) -------------
__global__ void transpose_cvt_w(const float* __restrict__ w0, const float* __restrict__ w1,
                                const float* __restrict__ w2, const float* __restrict__ w3,
                                _Float16* __restrict__ o0, _Float16* __restrict__ o1,
                                _Float16* __restrict__ o2, _Float16* __restrict__ o3) {
  const float* w; _Float16* o;
  switch (blockIdx.z) {
    case 0: w = w0; o = o0; break;
    case 1: w = w1; o = o1; break;
    case 2: w = w2; o = o2; break;
    default: w = w3; o = o3; break;
  }
  __shared__ alignas(16) _Float16 tile[64][72];
  const int kt = blockIdx.x * 64;
  const int nt = blockIdx.y * 64;
  const int tr = threadIdx.x >> 4;
  const int tc = threadIdx.x & 15;
#pragma unroll
  for (int rr = 0; rr < 4; ++rr) {
    int r = rr * 16 + tr;
    float4 v = *(const float4*)&w[(size_t)(kt + r) * kDim + nt + tc * 4];
    f16x4 hv;
    hv[0] = (_Float16)v.x; hv[1] = (_Float16)v.y; hv[2] = (_Float16)v.z; hv[3] = (_Float16)v.w;
    *(f16x4*)&tile[r][tc * 4] = hv;
  }
  __syncthreads();
#pragma unroll
  for (int rr = 0; rr < 4; ++rr) {
    int nl = rr * 16 + tr;
    f16x4 hv;
    hv[0] = tile[tc * 4 + 0][nl];
    hv[1] = tile[tc * 4 + 1][nl];
    hv[2] = tile[tc * 4 + 2][nl];
    hv[3] = tile[tc * 4 + 3][nl];
    *(f16x4*)&o[(size_t)(nt + nl) * kDim + kt + tc * 4] = hv;
  }
}

// ------------- QKV projection GEMM v3: global_load_lds staging -------------
// R11: replace reg-staging (load->VGPR->ds_write) with async global_load_lds
// 16B (m151: 874 vs 646 TF on this exact structure). T3 2-phase recipe:
// stage(next) -> ds_read(cur) -> MFMA -> vmcnt(0)+barrier. Linear LDS
// [row][64] + inverse-swizzled SOURCE (col chunk ^= row&7, folded into the
// per-lane source base ONCE) + swizzled READ (two lane-constant slot offsets
// + imm t*2048) = zero per-iter address VALU, 2 lanes/bank on ds_read_b128.
__global__ __launch_bounds__(256, 2) void gemm_qkv(
    const _Float16* __restrict__ A,
    const _Float16* __restrict__ wt0, const _Float16* __restrict__ wt1, const _Float16* __restrict__ wt2,
    const float* __restrict__ bias0, const float* __restrict__ bias1, const float* __restrict__ bias2,
    _Float16* __restrict__ oq, _Float16* __restrict__ ok, _Float16* __restrict__ ov) {
  const _Float16* Bt; const float* bias; _Float16* out;
  switch (blockIdx.z) {
    case 0: Bt = wt0; bias = bias0; out = oq; break;
    case 1: Bt = wt1; bias = bias1; out = ok; break;
    default: Bt = wt2; bias = bias2; out = ov; break;
  }
  __shared__ alignas(16) _Float16 As[2][128 * 64];
  __shared__ alignas(16) _Float16 Bs[2][128 * 64];
  const int tid = threadIdx.x;
  const int lane = tid & 63;
  const int wave = tid >> 6;
  const int wm = wave & 1, wn = wave >> 1;
  const int l15 = lane & 15, quad = lane >> 4;
  const int m0 = blockIdx.x * 128, n0 = blockIdx.y * 128;

  // staging: wave w covers rows w*32 + g*8 + (lane>>3), g=0..3; lane's 16B
  // source chunk is (lane&7) ^ (row&7)  [inverse swizzle; row&7 == lane>>3]
  const int grow = lane >> 3;                       // 0..7
  const int gcol = ((lane & 7) ^ grow) * 8;         // f16 units
  const _Float16* Asrc = A  + (size_t)(m0 + wave * 32 + grow) * kDim + gcol;
  const _Float16* Bsrc = Bt + (size_t)(n0 + wave * 32 + grow) * kDim + gcol;

  // read: row r holds k-chunk c at slot c^(r&7); af rows = wm*64+t*16+l15
  const int xr = l15 & 7;
  const int slotA0 = ((quad) ^ xr) * 16, slotA1 = ((4 + quad) ^ xr) * 16;  // bytes
  const int rbaseA = (wm * 64 + l15) * 128;
  const int rbaseB = (wn * 64 + l15) * 128;

  f32x4 acc[4][4] = {};

  // prologue: stage tile 0 into buffer 0
#pragma unroll
  for (int g = 0; g < 4; ++g) {
    gload16(Asrc + (size_t)g * 8 * kDim, (char*)&As[0][0] + (wave * 32 + g * 8) * 128);
    gload16(Bsrc + (size_t)g * 8 * kDim, (char*)&Bs[0][0] + (wave * 32 + g * 8) * 128);
  }
  wg_barrier_vm();

  for (int kt = 0; kt < 16; ++kt) {
    const int cur = kt & 1;
    if (kt + 1 < 16) {  // stage next tile (async; lands during MFMA below)
      int koff = (kt + 1) * 64;
#pragma unroll
      for (int g = 0; g < 4; ++g) {
        gload16(Asrc + (size_t)g * 8 * kDim + koff, (char*)&As[cur ^ 1][0] + (wave * 32 + g * 8) * 128);
        gload16(Bsrc + (size_t)g * 8 * kDim + koff, (char*)&Bs[cur ^ 1][0] + (wave * 32 + g * 8) * 128);
      }
    }
#pragma unroll
    for (int kk = 0; kk < 2; ++kk) {
      const int sa = kk ? slotA1 : slotA0;
      f16x8 af[4], bf[4];
#pragma unroll
      for (int t = 0; t < 4; ++t) af[t] = *(const f16x8*)((const char*)&As[cur][0] + rbaseA + t * 2048 + sa);
#pragma unroll
      for (int t = 0; t < 4; ++t) bf[t] = *(const f16x8*)((const char*)&Bs[cur][0] + rbaseB + t * 2048 + sa);
      __builtin_amdgcn_s_setprio(1);
#pragma unroll
      for (int i = 0; i < 4; ++i)
#pragma unroll
        for (int j = 0; j < 4; ++j)
          acc[i][j] = MFMA_16x16x32(af[i], bf[j], acc[i][j]);
      __builtin_amdgcn_s_setprio(0);
    }
    if (kt + 1 < 16) wg_barrier_vm();  // next buffer fully staged; reads done
  }

  const int mbase = m0 + wm * 64 + quad * 4;
  const int nbase = n0 + wn * 64 + l15;
  if (blockIdx.z == 2) {
#pragma unroll
    for (int j = 0; j < 4; ++j) {
      int n = nbase + j * 16;
      float bv = bias[n];
      int h = n >> 6, d = n & 63;
#pragma unroll
      for (int i = 0; i < 4; ++i) {
        int m = mbase + i * 16;
        int b = m >> 11, s = m & (kS - 1);
        f16x4 hv;
#pragma unroll
        for (int r = 0; r < 4; ++r) hv[r] = (_Float16)(acc[i][j][r] + bv);
        *(f16x4*)&out[((size_t)((b * kH + h) * kD + d)) * kS + s] = hv;
      }
    }
  } else {
    const float osc = (blockIdx.z == 0) ? kQScale : 1.0f;
#pragma unroll
    for (int j = 0; j < 4; ++j) {
      int n = nbase + j * 16;
      float bv = bias[n];
      int h = n >> 6, d = n & 63;
#pragma unroll
      for (int i = 0; i < 4; ++i) {
        int mrow = mbase + i * 16;
#pragma unroll
        for (int r = 0; r < 4; ++r) {
          int m = mrow + r;
          int b = m >> 11, s = m & (kS - 1);
          out[(size_t)(((b * kH + h) * kS) + s) * kD + d] = (_Float16)((acc[i][j][r] + bv) * osc);
        }
      }
    }
  }
}

// ------------- flash attention, S^T formulation, v7 (R9-measured 64.7us) -----
// R10 post-mortem: key-parallel 512-thr variant REGRESSED (occupancy 2x but
// per-wave issue rate halved -> VALU+MFMA issue-throughput-bound, not
// latency-bound). Reverted to the measured-best v7.
__global__ __launch_bounds__(256, 2) void attn(
    const _Float16* __restrict__ Q, const _Float16* __restrict__ K,
    const _Float16* __restrict__ V, const float* __restrict__ mask,
    _Float16* __restrict__ ctx) {
  const int id = blockIdx.x;
  const int logical = (id & 7) * 64 + (id >> 3);
  const int bh = logical >> 4;    // 0..31
  const int qblk = logical & 15;  // 0..15
  const int b = bh >> 4;
  const int q0 = qblk * 128;
  const int tid = threadIdx.x, lane = tid & 63, wave = tid >> 6;
  const int l15 = lane & 15, quad = lane >> 4;

  __shared__ alignas(16) _Float16 Ks[2][128 * 72];  // [key][d], stride 144B
  __shared__ alignas(16) _Float16 Vs[2][64 * 136];  // [d][key], stride 272B
  __shared__ alignas(16) float pens[kS];            // (mask-1)*kPenC for all keys

  const _Float16* Qh = Q + (size_t)bh * kS * kD;
  const _Float16* Kh = K + (size_t)bh * kS * kD;
  const _Float16* Vh = V + (size_t)bh * kS * kD;  // [d][s]

#pragma unroll
  for (int i = 0; i < 2; ++i) {
    float4 mv4 = *(const float4*)&mask[(size_t)b * kS + tid * 8 + i * 4];
    float4 pv;
    pv.x = (mv4.x - 1.0f) * kPenC;
    pv.y = (mv4.y - 1.0f) * kPenC;
    pv.z = (mv4.z - 1.0f) * kPenC;
    pv.w = (mv4.w - 1.0f) * kPenC;
    *(float4*)&pens[tid * 8 + i * 4] = pv;
  }

  f16x8 qf[2][2];
#pragma unroll
  for (int t = 0; t < 2; ++t) {
    int qrow = q0 + wave * 32 + t * 16 + l15;
#pragma unroll
    for (int kk = 0; kk < 2; ++kk)
      qf[t][kk] = *(const f16x8*)&Qh[(size_t)qrow * kD + kk * 32 + quad * 8];
  }

  f16x4 ones4;
#pragma unroll
  for (int i = 0; i < 4; ++i) ones4[i] = (_Float16)1.0f;

  f32x4 o_acc[2][4] = {};  // O[q][d]: lane holds q=quad*4+r, d=c*16+l15
  f32x4 l_acc[2] = {};     // l[q=quad*4+r]

  const int srow = tid >> 3;        // K staging row base (0..31)
  const int skc = (tid & 7) * 8;    // K staging d-offset
  const int vrow = tid >> 4;        // V staging row base (0..15)
  const int vcol = (tid & 15) * 8;  // V staging key-offset

  f16x8 kreg[4], vreg[4];
#pragma unroll
  for (int i = 0; i < 4; ++i)
    kreg[i] = *(const f16x8*)&Kh[(size_t)(srow + 32 * i) * kD + skc];
#pragma unroll
  for (int i = 0; i < 4; ++i)
    vreg[i] = *(const f16x8*)&Vh[(size_t)(vrow + 16 * i) * kS + vcol];
#pragma unroll
  for (int i = 0; i < 4; ++i)
    *(f16x8*)&Ks[0][(srow + 32 * i) * 72 + skc] = kreg[i];
#pragma unroll
  for (int i = 0; i < 4; ++i)
    *(f16x8*)&Vs[0][(vrow + 16 * i) * 136 + vcol] = vreg[i];

  for (int it = 0; it < 16; ++it) {
    const int cur = it & 1;
    const int kb = it * 128;
    if (it + 1 < 16) {  // issue next K/V tiles; fly under compute (no vmcnt drain)
#pragma unroll
      for (int i = 0; i < 4; ++i)
        kreg[i] = *(const f16x8*)&Kh[(size_t)(kb + 128 + srow + 32 * i) * kD + skc];
#pragma unroll
      for (int i = 0; i < 4; ++i)
        vreg[i] = *(const f16x8*)&Vh[(size_t)(vrow + 16 * i) * kS + kb + 128 + vcol];
    }
    wg_barrier_lds();  // buf[cur] staged (prev iter / prologue); prev reads of buf[cur] done

#pragma unroll
    for (int colt = 0; colt < 8; ++colt) {
      f32x4 pn = *(const f32x4*)&pens[kb + colt * 16 + quad * 4];
      f16x8 kf0 = *(const f16x8*)&Ks[cur][(colt * 16 + l15) * 72 + quad * 8];
      f16x8 kf1 = *(const f16x8*)&Ks[cur][(colt * 16 + l15) * 72 + 32 + quad * 8];
      f32x4 s0 = pn, s1 = pn;
      s0 = MFMA_16x16x32(kf0, qf[0][0], s0);
      s0 = MFMA_16x16x32(kf1, qf[0][1], s0);
      s1 = MFMA_16x16x32(kf0, qf[1][0], s1);
      s1 = MFMA_16x16x32(kf1, qf[1][1], s1);
      f16x4 vf0 = *(const f16x4*)&Vs[cur][(0 * 16 + l15) * 136 + colt * 16 + quad * 4];
      f16x4 vf1 = *(const f16x4*)&Vs[cur][(1 * 16 + l15) * 136 + colt * 16 + quad * 4];
      f16x4 vf2 = *(const f16x4*)&Vs[cur][(2 * 16 + l15) * 136 + colt * 16 + quad * 4];
      f16x4 vf3 = *(const f16x4*)&Vs[cur][(3 * 16 + l15) * 136 + colt * 16 + quad * 4];
      f16x4 pa0, pa1;
#pragma unroll
      for (int r = 0; r < 4; ++r) {
        pa0[r] = (_Float16)__builtin_exp2f(s0[r]);
        pa1[r] = (_Float16)__builtin_exp2f(s1[r]);
      }
      __builtin_amdgcn_s_setprio(1);
      o_acc[0][0] = MFMA_16x16x16(pa0, vf0, o_acc[0][0]);
      o_acc[0][1] = MFMA_16x16x16(pa0, vf1, o_acc[0][1]);
      o_acc[0][2] = MFMA_16x16x16(pa0, vf2, o_acc[0][2]);
      o_acc[0][3] = MFMA_16x16x16(pa0, vf3, o_acc[0][3]);
      o_acc[1][0] = MFMA_16x16x16(pa1, vf0, o_acc[1][0]);
      o_acc[1][1] = MFMA_16x16x16(pa1, vf1, o_acc[1][1]);
      o_acc[1][2] = MFMA_16x16x16(pa1, vf2, o_acc[1][2]);
      o_acc[1][3] = MFMA_16x16x16(pa1, vf3, o_acc[1][3]);
      l_acc[0] = MFMA_16x16x16(pa0, ones4, l_acc[0]);
      l_acc[1] = MFMA_16x16x16(pa1, ones4, l_acc[1]);
      __builtin_amdgcn_s_setprio(0);
    }

    if (it + 1 < 16) {
#pragma unroll
      for (int i = 0; i < 4; ++i)
        *(f16x8*)&Ks[cur ^ 1][(srow + 32 * i) * 72 + skc] = kreg[i];
#pragma unroll
      for (int i = 0; i < 4; ++i)
        *(f16x8*)&Vs[cur ^ 1][(vrow + 16 * i) * 136 + vcol] = vreg[i];
    }
  }

  const int h = bh & 15;
#pragma unroll
  for (int t = 0; t < 2; ++t) {
    f32x4 linv;
#pragma unroll
    for (int r = 0; r < 4; ++r) linv[r] = 1.0f / l_acc[t][r];
    int qbase = q0 + wave * 32 + t * 16 + quad * 4;
#pragma unroll
    for (int c = 0; c < 4; ++c) {
#pragma unroll
      for (int r = 0; r < 4; ++r) {
        ctx[((size_t)(b * kS + qbase + r)) * kDim + h * kD + c * 16 + l15] =
            (_Float16)(o_acc[t][c][r] * linv[r]);
      }
    }
  }
}

// ------------- output GEMM v3: global_load_lds staging (same recipe) -------------
__global__ __launch_bounds__(256, 2) void gemm_out(
    const _Float16* __restrict__ A, const _Float16* __restrict__ Bt,
    const float* __restrict__ bias, float* __restrict__ out) {
  __shared__ alignas(16) _Float16 As[2][64 * 64];
  __shared__ alignas(16) _Float16 Bs[2][128 * 64];
  const int tid = threadIdx.x;
  const int lane = tid & 63;
  const int wave = tid >> 6;
  const int wm = wave & 1, wn = wave >> 1;   // 2x2 waves: 32M x 64N each
  const int l15 = lane & 15, quad = lane >> 4;
  const int m0 = blockIdx.x * 64, n0 = blockIdx.y * 128;

  const int grow = lane >> 3;
  const int gcol = ((lane & 7) ^ grow) * 8;
  const _Float16* Asrc = A  + (size_t)(m0 + wave * 16 + grow) * kDim + gcol;  // g=0..1
  const _Float16* Bsrc = Bt + (size_t)(n0 + wave * 32 + grow) * kDim + gcol;  // g=0..3

  const int xr = l15 & 7;
  const int slot0 = ((quad) ^ xr) * 16, slot1 = ((4 + quad) ^ xr) * 16;
  const int rbaseA = (wm * 32 + l15) * 128;
  const int rbaseB = (wn * 64 + l15) * 128;

  f32x4 acc[2][4] = {};

#pragma unroll
  for (int g = 0; g < 2; ++g)
    gload16(Asrc + (size_t)g * 8 * kDim, (char*)&As[0][0] + (wave * 16 + g * 8) * 128);
#pragma unroll
  for (int g = 0; g < 4; ++g)
    gload16(Bsrc + (size_t)g * 8 * kDim, (char*)&Bs[0][0] + (wave * 32 + g * 8) * 128);
  wg_barrier_vm();

  for (int kt = 0; kt < 16; ++kt) {
    const int cur = kt & 1;
    if (kt + 1 < 16) {
      int koff = (kt + 1) * 64;
#pragma unroll
      for (int g = 0; g < 2; ++g)
        gload16(Asrc + (size_t)g * 8 * kDim + koff, (char*)&As[cur ^ 1][0] + (wave * 16 + g * 8) * 128);
#pragma unroll
      for (int g = 0; g < 4; ++g)
        gload16(Bsrc + (size_t)g * 8 * kDim + koff, (char*)&Bs[cur ^ 1][0] + (wave * 32 + g * 8) * 128);
    }
#pragma unroll
    for (int kk = 0; kk < 2; ++kk) {
      const int sa = kk ? slot1 : slot0;
      f16x8 af[2], bf[4];
#pragma unroll
      for (int t = 0; t < 2; ++t) af[t] = *(const f16x8*)((const char*)&As[cur][0] + rbaseA + t * 2048 + sa);
#pragma unroll
      for (int t = 0; t < 4; ++t) bf[t] = *(const f16x8*)((const char*)&Bs[cur][0] + rbaseB + t * 2048 + sa);
      __builtin_amdgcn_s_setprio(1);
#pragma unroll
      for (int i = 0; i < 2; ++i)
#pragma unroll
        for (int j = 0; j < 4; ++j)
          acc[i][j] = MFMA_16x16x32(af[i], bf[j], acc[i][j]);
      __builtin_amdgcn_s_setprio(0);
    }
    if (kt + 1 < 16) wg_barrier_vm();
  }

  const int mbase = m0 + wm * 32 + quad * 4;
  const int nbase = n0 + wn * 64 + l15;
#pragma unroll
  for (int j = 0; j < 4; ++j) {
    int n = nbase + j * 16;
    float bv = bias[n];
#pragma unroll
    for (int i = 0; i < 2; ++i) {
      int mrow = mbase + i * 16;
#pragma unroll
      for (int r = 0; r < 4; ++r)
        out[(size_t)(mrow + r) * kDim + n] = acc[i][j][r] + bv;
    }
  }
}

extern "C" void kernel_launch(void* const* d_in, const int* in_sizes, int n_in,
                              void* d_out, int out_size, void* d_ws, size_t ws_size,
                              hipStream_t stream) {
  (void)in_sizes; (void)n_in; (void)out_size; (void)ws_size;
  const float* X    = (const float*)d_in[0];
  const float* mask = (const float*)d_in[1];
  const float* Wq   = (const float*)d_in[2];
  const float* bq   = (const float*)d_in[3];
  const float* Wk   = (const float*)d_in[4];
  const float* bk   = (const float*)d_in[5];
  const float* Wv   = (const float*)d_in[6];
  const float* bv   = (const float*)d_in[7];
  const float* Wo   = (const float*)d_in[8];
  const float* bo   = (const float*)d_in[9];
  float* out = (float*)d_out;

  char* ws = (char*)d_ws;
  _Float16* Xh   = (_Float16*)(ws);                        // 8 MB
  _Float16* Wqt  = (_Float16*)(ws + ((size_t)8  << 20));   // 2 MB each
  _Float16* Wkt  = (_Float16*)(ws + ((size_t)10 << 20));
  _Float16* Wvt  = (_Float16*)(ws + ((size_t)12 << 20));
  _Float16* Wot  = (_Float16*)(ws + ((size_t)14 << 20));
  _Float16* Qh   = (_Float16*)(ws + ((size_t)16 << 20));   // 8 MB each
  _Float16* Kh   = (_Float16*)(ws + ((size_t)24 << 20));
  _Float16* Vh   = (_Float16*)(ws + ((size_t)32 << 20));   // [B][H][D][S]
  _Float16* Ch   = (_Float16*)(ws + ((size_t)40 << 20));   // 8 MB

  cvt_f32_to_f16<<<dim3(kM * kDim / 8 / 256), dim3(256), 0, stream>>>(X, Xh, kM * kDim / 8);
  transpose_cvt_w<<<dim3(16, 16, 4), dim3(256), 0, stream>>>(Wq, Wk, Wv, Wo, Wqt, Wkt, Wvt, Wot);
  gemm_qkv<<<dim3(32, 8, 3), dim3(256), 0, stream>>>(Xh, Wqt, Wkt, Wvt, bq, bk, bv, Qh, Kh, Vh);
  attn<<<dim3(512), dim3(256), 0, stream>>>(Qh, Kh, Vh, mask, Ch);
  gemm_out<<<dim3(64, 8), dim3(256), 0, stream>>>(Ch, Wot, bo, out);
}

// Round 12
// 200.714 us; speedup vs baseline: 1.0308x; 1.0205x over previous
//
#include <hip/hip_runtime.h>
#include <cstdint>
#include <cstddef>

typedef __attribute__((ext_vector_type(8))) _Float16 f16x8;
typedef __attribute__((ext_vector_type(4))) _Float16 f16x4;
typedef __attribute__((ext_vector_type(4))) float f32x4;

#define MFMA_16x16x32(a, b, c) __builtin_amdgcn_mfma_f32_16x16x32_f16((a), (b), (c), 0, 0, 0)
#define MFMA_16x16x16(a, b, c) __builtin_amdgcn_mfma_f32_16x16x16f16((a), (b), (c), 0, 0, 0)

static constexpr int kB = 2, kS = 2048, kDim = 1024, kH = 16, kD = 64;
static constexpr int kM = kB * kS;  // 4096 rows total
// 1/sqrt(64) * log2(e), folded into Q at projection time
static constexpr float kQScale = 0.125f * 1.44269504088896340736f;
// -1e6 * log2(e): mask penalty in exp2 domain
static constexpr float kPenC = 1.44269504088896340736e6f;

// Raw workgroup barrier: drain only LDS ops (lgkmcnt), NOT vmcnt, so register
// prefetch loads stay in flight across the barrier (in-order vmcnt retire:
// the later s_waitcnt before ds_write of the prefetched regs orders them).
__device__ __forceinline__ void wg_barrier_lds() {
  asm volatile("s_waitcnt lgkmcnt(0)" ::: "memory");
  __builtin_amdgcn_s_barrier();
}

// ---------------- elementwise f32 -> f16 ----------------
__global__ void cvt_f32_to_f16(const float* __restrict__ in, _Float16* __restrict__ out, int n8) {
  int i = blockIdx.x * blockDim.x + threadIdx.x;
  if (i >= n8) return;
  const float4* p = (const float4*)in + (size_t)i * 2;
  float4 a = p[0], b = p[1];
  f16x8 h;
  h[0] = (_Float16)a.x; h[1] = (_Float16)a.y; h[2] = (_Float16)a.z; h[3] = (_Float16)a.w;
  h[4] = (_Float16)b.x; h[5] = (_Float16)b.y; h[6] = (_Float16)b.z; h[7] = (_Float16)b.w;
  ((f16x8*)out)[i] = h;
}

// ------------- W [K][N] f32  ->  Wt [N][K] f16 (4 matrices) -------------
__global__ void transpose_cvt_w(const float* __restrict__ w0, const float* __restrict__ w1,
                                const float* __restrict__ w2, const float* __restrict__ w3,
                                _Float16* __restrict__ o0, _Float16* __restrict__ o1,
                                _Float16* __restrict__ o2, _Float16* __restrict__ o3) {
  const float* w; _Float16* o;
  switch (blockIdx.z) {
    case 0: w = w0; o = o0; break;
    case 1: w = w1; o = o1; break;
    case 2: w = w2; o = o2; break;
    default: w = w3; o = o3; break;
  }
  __shared__ alignas(16) _Float16 tile[64][72];
  const int kt = blockIdx.x * 64;
  const int nt = blockIdx.y * 64;
  const int tr = threadIdx.x >> 4;
  const int tc = threadIdx.x & 15;
#pragma unroll
  for (int rr = 0; rr < 4; ++rr) {
    int r = rr * 16 + tr;
    float4 v = *(const float4*)&w[(size_t)(kt + r) * kDim + nt + tc * 4];
    f16x4 hv;
    hv[0] = (_Float16)v.x; hv[1] = (_Float16)v.y; hv[2] = (_Float16)v.z; hv[3] = (_Float16)v.w;
    *(f16x4*)&tile[r][tc * 4] = hv;
  }
  __syncthreads();
#pragma unroll
  for (int rr = 0; rr < 4; ++rr) {
    int nl = rr * 16 + tr;
    f16x4 hv;
    hv[0] = tile[tc * 4 + 0][nl];
    hv[1] = tile[tc * 4 + 1][nl];
    hv[2] = tile[tc * 4 + 2][nl];
    hv[3] = tile[tc * 4 + 3][nl];
    *(f16x4*)&o[(size_t)(nt + nl) * kDim + kt + tc * 4] = hv;
  }
}

// ------------- QKV projection GEMM (R7-measured best: BK=64, reg-staged,
// lgkm-only barriers keep prefetch loads in flight across the barrier).
// R11 post-mortem: global_load_lds + vmcnt(0)-drain barrier REGRESSED (+12us)
// -- it discards the cross-barrier load pipelining this structure already has.
__global__ __launch_bounds__(256, 2) void gemm_qkv(
    const _Float16* __restrict__ A,
    const _Float16* __restrict__ wt0, const _Float16* __restrict__ wt1, const _Float16* __restrict__ wt2,
    const float* __restrict__ bias0, const float* __restrict__ bias1, const float* __restrict__ bias2,
    _Float16* __restrict__ oq, _Float16* __restrict__ ok, _Float16* __restrict__ ov) {
  const _Float16* Bt; const float* bias; _Float16* out;
  switch (blockIdx.z) {
    case 0: Bt = wt0; bias = bias0; out = oq; break;
    case 1: Bt = wt1; bias = bias1; out = ok; break;
    default: Bt = wt2; bias = bias2; out = ov; break;
  }
  __shared__ alignas(16) _Float16 As[2][128 * 72];
  __shared__ alignas(16) _Float16 Bs[2][128 * 72];
  const int tid = threadIdx.x;
  const int lane = tid & 63;
  const int wave = tid >> 6;
  const int wm = wave & 1, wn = wave >> 1;
  const int l15 = lane & 15, quad = lane >> 4;
  const int m0 = blockIdx.x * 128, n0 = blockIdx.y * 128;

  const int srow = tid >> 3;             // staging row (tid + 256*i -> row = srow + 32*i)
  const int skc = (tid & 7) * 8;         // staging k-offset

  f32x4 acc[4][4] = {};
  f16x8 ra[4], rb[4];

#pragma unroll
  for (int i = 0; i < 4; ++i) {
    int row = srow + 32 * i;
    ra[i] = *(const f16x8*)&A[(size_t)(m0 + row) * kDim + skc];
    rb[i] = *(const f16x8*)&Bt[(size_t)(n0 + row) * kDim + skc];
  }
#pragma unroll
  for (int i = 0; i < 4; ++i) {
    int row = srow + 32 * i;
    *(f16x8*)&As[0][row * 72 + skc] = ra[i];
    *(f16x8*)&Bs[0][row * 72 + skc] = rb[i];
  }

  for (int kt = 0; kt < 16; ++kt) {
    const int cur = kt & 1;
    if (kt + 1 < 16) {
      int k0 = (kt + 1) * 64;
#pragma unroll
      for (int i = 0; i < 4; ++i) {
        int row = srow + 32 * i;
        ra[i] = *(const f16x8*)&A[(size_t)(m0 + row) * kDim + k0 + skc];
        rb[i] = *(const f16x8*)&Bt[(size_t)(n0 + row) * kDim + k0 + skc];
      }
    }
    wg_barrier_lds();  // writes to buffer `cur` (prev iter / prologue) complete
#pragma unroll
    for (int kk = 0; kk < 2; ++kk) {
      f16x8 af[4], bf[4];
#pragma unroll
      for (int t = 0; t < 4; ++t) af[t] = *(const f16x8*)&As[cur][(wm * 64 + t * 16 + l15) * 72 + kk * 32 + quad * 8];
#pragma unroll
      for (int t = 0; t < 4; ++t) bf[t] = *(const f16x8*)&Bs[cur][(wn * 64 + t * 16 + l15) * 72 + kk * 32 + quad * 8];
      __builtin_amdgcn_s_setprio(1);
#pragma unroll
      for (int i = 0; i < 4; ++i)
#pragma unroll
        for (int j = 0; j < 4; ++j)
          acc[i][j] = MFMA_16x16x32(af[i], bf[j], acc[i][j]);
      __builtin_amdgcn_s_setprio(0);
    }
    if (kt + 1 < 16) {
#pragma unroll
      for (int i = 0; i < 4; ++i) {
        int row = srow + 32 * i;
        *(f16x8*)&As[cur ^ 1][row * 72 + skc] = ra[i];
        *(f16x8*)&Bs[cur ^ 1][row * 72 + skc] = rb[i];
      }
    }
  }

  const int mbase = m0 + wm * 64 + quad * 4;
  const int nbase = n0 + wn * 64 + l15;
  if (blockIdx.z == 2) {
#pragma unroll
    for (int j = 0; j < 4; ++j) {
      int n = nbase + j * 16;
      float bv = bias[n];
      int h = n >> 6, d = n & 63;
#pragma unroll
      for (int i = 0; i < 4; ++i) {
        int m = mbase + i * 16;
        int b = m >> 11, s = m & (kS - 1);
        f16x4 hv;
#pragma unroll
        for (int r = 0; r < 4; ++r) hv[r] = (_Float16)(acc[i][j][r] + bv);
        *(f16x4*)&out[((size_t)((b * kH + h) * kD + d)) * kS + s] = hv;
      }
    }
  } else {
    const float osc = (blockIdx.z == 0) ? kQScale : 1.0f;
#pragma unroll
    for (int j = 0; j < 4; ++j) {
      int n = nbase + j * 16;
      float bv = bias[n];
      int h = n >> 6, d = n & 63;
#pragma unroll
      for (int i = 0; i < 4; ++i) {
        int mrow = mbase + i * 16;
#pragma unroll
        for (int r = 0; r < 4; ++r) {
          int m = mrow + r;
          int b = m >> 11, s = m & (kS - 1);
          out[(size_t)(((b * kH + h) * kS) + s) * kD + d] = (_Float16)((acc[i][j][r] + bv) * osc);
        }
      }
    }
  }
}

// ------------- flash attention, S^T formulation, v7 (R9/R11-measured 64.7-64.9us) -----
__global__ __launch_bounds__(256, 2) void attn(
    const _Float16* __restrict__ Q, const _Float16* __restrict__ K,
    const _Float16* __restrict__ V, const float* __restrict__ mask,
    _Float16* __restrict__ ctx) {
  const int id = blockIdx.x;
  const int logical = (id & 7) * 64 + (id >> 3);
  const int bh = logical >> 4;    // 0..31
  const int qblk = logical & 15;  // 0..15
  const int b = bh >> 4;
  const int q0 = qblk * 128;
  const int tid = threadIdx.x, lane = tid & 63, wave = tid >> 6;
  const int l15 = lane & 15, quad = lane >> 4;

  __shared__ alignas(16) _Float16 Ks[2][128 * 72];  // [key][d], stride 144B
  __shared__ alignas(16) _Float16 Vs[2][64 * 136];  // [d][key], stride 272B
  __shared__ alignas(16) float pens[kS];            // (mask-1)*kPenC for all keys

  const _Float16* Qh = Q + (size_t)bh * kS * kD;
  const _Float16* Kh = K + (size_t)bh * kS * kD;
  const _Float16* Vh = V + (size_t)bh * kS * kD;  // [d][s]

#pragma unroll
  for (int i = 0; i < 2; ++i) {
    float4 mv4 = *(const float4*)&mask[(size_t)b * kS + tid * 8 + i * 4];
    float4 pv;
    pv.x = (mv4.x - 1.0f) * kPenC;
    pv.y = (mv4.y - 1.0f) * kPenC;
    pv.z = (mv4.z - 1.0f) * kPenC;
    pv.w = (mv4.w - 1.0f) * kPenC;
    *(float4*)&pens[tid * 8 + i * 4] = pv;
  }

  f16x8 qf[2][2];
#pragma unroll
  for (int t = 0; t < 2; ++t) {
    int qrow = q0 + wave * 32 + t * 16 + l15;
#pragma unroll
    for (int kk = 0; kk < 2; ++kk)
      qf[t][kk] = *(const f16x8*)&Qh[(size_t)qrow * kD + kk * 32 + quad * 8];
  }

  f16x4 ones4;
#pragma unroll
  for (int i = 0; i < 4; ++i) ones4[i] = (_Float16)1.0f;

  f32x4 o_acc[2][4] = {};  // O[q][d]: lane holds q=quad*4+r, d=c*16+l15
  f32x4 l_acc[2] = {};     // l[q=quad*4+r]

  const int srow = tid >> 3;        // K staging row base (0..31)
  const int skc = (tid & 7) * 8;    // K staging d-offset
  const int vrow = tid >> 4;        // V staging row base (0..15)
  const int vcol = (tid & 15) * 8;  // V staging key-offset

  f16x8 kreg[4], vreg[4];
#pragma unroll
  for (int i = 0; i < 4; ++i)
    kreg[i] = *(const f16x8*)&Kh[(size_t)(srow + 32 * i) * kD + skc];
#pragma unroll
  for (int i = 0; i < 4; ++i)
    vreg[i] = *(const f16x8*)&Vh[(size_t)(vrow + 16 * i) * kS + vcol];
#pragma unroll
  for (int i = 0; i < 4; ++i)
    *(f16x8*)&Ks[0][(srow + 32 * i) * 72 + skc] = kreg[i];
#pragma unroll
  for (int i = 0; i < 4; ++i)
    *(f16x8*)&Vs[0][(vrow + 16 * i) * 136 + vcol] = vreg[i];

  for (int it = 0; it < 16; ++it) {
    const int cur = it & 1;
    const int kb = it * 128;
    if (it + 1 < 16) {  // issue next K/V tiles; fly under compute (no vmcnt drain)
#pragma unroll
      for (int i = 0; i < 4; ++i)
        kreg[i] = *(const f16x8*)&Kh[(size_t)(kb + 128 + srow + 32 * i) * kD + skc];
#pragma unroll
      for (int i = 0; i < 4; ++i)
        vreg[i] = *(const f16x8*)&Vh[(size_t)(vrow + 16 * i) * kS + kb + 128 + vcol];
    }
    wg_barrier_lds();  // buf[cur] staged (prev iter / prologue); prev reads of buf[cur] done

#pragma unroll
    for (int colt = 0; colt < 8; ++colt) {
      f32x4 pn = *(const f32x4*)&pens[kb + colt * 16 + quad * 4];
      f16x8 kf0 = *(const f16x8*)&Ks[cur][(colt * 16 + l15) * 72 + quad * 8];
      f16x8 kf1 = *(const f16x8*)&Ks[cur][(colt * 16 + l15) * 72 + 32 + quad * 8];
      f32x4 s0 = pn, s1 = pn;
      s0 = MFMA_16x16x32(kf0, qf[0][0], s0);
      s0 = MFMA_16x16x32(kf1, qf[0][1], s0);
      s1 = MFMA_16x16x32(kf0, qf[1][0], s1);
      s1 = MFMA_16x16x32(kf1, qf[1][1], s1);
      f16x4 vf0 = *(const f16x4*)&Vs[cur][(0 * 16 + l15) * 136 + colt * 16 + quad * 4];
      f16x4 vf1 = *(const f16x4*)&Vs[cur][(1 * 16 + l15) * 136 + colt * 16 + quad * 4];
      f16x4 vf2 = *(const f16x4*)&Vs[cur][(2 * 16 + l15) * 136 + colt * 16 + quad * 4];
      f16x4 vf3 = *(const f16x4*)&Vs[cur][(3 * 16 + l15) * 136 + colt * 16 + quad * 4];
      f16x4 pa0, pa1;
#pragma unroll
      for (int r = 0; r < 4; ++r) {
        pa0[r] = (_Float16)__builtin_exp2f(s0[r]);
        pa1[r] = (_Float16)__builtin_exp2f(s1[r]);
      }
      __builtin_amdgcn_s_setprio(1);
      o_acc[0][0] = MFMA_16x16x16(pa0, vf0, o_acc[0][0]);
      o_acc[0][1] = MFMA_16x16x16(pa0, vf1, o_acc[0][1]);
      o_acc[0][2] = MFMA_16x16x16(pa0, vf2, o_acc[0][2]);
      o_acc[0][3] = MFMA_16x16x16(pa0, vf3, o_acc[0][3]);
      o_acc[1][0] = MFMA_16x16x16(pa1, vf0, o_acc[1][0]);
      o_acc[1][1] = MFMA_16x16x16(pa1, vf1, o_acc[1][1]);
      o_acc[1][2] = MFMA_16x16x16(pa1, vf2, o_acc[1][2]);
      o_acc[1][3] = MFMA_16x16x16(pa1, vf3, o_acc[1][3]);
      l_acc[0] = MFMA_16x16x16(pa0, ones4, l_acc[0]);
      l_acc[1] = MFMA_16x16x16(pa1, ones4, l_acc[1]);
      __builtin_amdgcn_s_setprio(0);
    }

    if (it + 1 < 16) {
#pragma unroll
      for (int i = 0; i < 4; ++i)
        *(f16x8*)&Ks[cur ^ 1][(srow + 32 * i) * 72 + skc] = kreg[i];
#pragma unroll
      for (int i = 0; i < 4; ++i)
        *(f16x8*)&Vs[cur ^ 1][(vrow + 16 * i) * 136 + vcol] = vreg[i];
    }
  }

  const int h = bh & 15;
#pragma unroll
  for (int t = 0; t < 2; ++t) {
    f32x4 linv;
#pragma unroll
    for (int r = 0; r < 4; ++r) linv[r] = 1.0f / l_acc[t][r];
    int qbase = q0 + wave * 32 + t * 16 + quad * 4;
#pragma unroll
    for (int c = 0; c < 4; ++c) {
#pragma unroll
      for (int r = 0; r < 4; ++r) {
        ctx[((size_t)(b * kS + qbase + r)) * kDim + h * kD + c * 16 + l15] =
            (_Float16)(o_acc[t][c][r] * linv[r]);
      }
    }
  }
}

// ------------- output GEMM (R7-measured: BM=64, BK=64 reg-staged, lgkm barriers) -------------
__global__ __launch_bounds__(256, 2) void gemm_out(
    const _Float16* __restrict__ A, const _Float16* __restrict__ Bt,
    const float* __restrict__ bias, float* __restrict__ out) {
  __shared__ alignas(16) _Float16 As[2][64 * 72];
  __shared__ alignas(16) _Float16 Bs[2][128 * 72];
  const int tid = threadIdx.x;
  const int lane = tid & 63;
  const int wave = tid >> 6;
  const int wm = wave & 1, wn = wave >> 1;   // 2x2 waves: 32M x 64N each
  const int l15 = lane & 15, quad = lane >> 4;
  const int m0 = blockIdx.x * 64, n0 = blockIdx.y * 128;

  const int srow = tid >> 3;
  const int skc = (tid & 7) * 8;

  f32x4 acc[2][4] = {};
  f16x8 ra[2], rb[4];

#pragma unroll
  for (int i = 0; i < 2; ++i)
    ra[i] = *(const f16x8*)&A[(size_t)(m0 + srow + 32 * i) * kDim + skc];
#pragma unroll
  for (int i = 0; i < 4; ++i)
    rb[i] = *(const f16x8*)&Bt[(size_t)(n0 + srow + 32 * i) * kDim + skc];
#pragma unroll
  for (int i = 0; i < 2; ++i)
    *(f16x8*)&As[0][(srow + 32 * i) * 72 + skc] = ra[i];
#pragma unroll
  for (int i = 0; i < 4; ++i)
    *(f16x8*)&Bs[0][(srow + 32 * i) * 72 + skc] = rb[i];

  for (int kt = 0; kt < 16; ++kt) {
    const int cur = kt & 1;
    if (kt + 1 < 16) {
      int k0 = (kt + 1) * 64;
#pragma unroll
      for (int i = 0; i < 2; ++i)
        ra[i] = *(const f16x8*)&A[(size_t)(m0 + srow + 32 * i) * kDim + k0 + skc];
#pragma unroll
      for (int i = 0; i < 4; ++i)
        rb[i] = *(const f16x8*)&Bt[(size_t)(n0 + srow + 32 * i) * kDim + k0 + skc];
    }
    wg_barrier_lds();
#pragma unroll
    for (int kk = 0; kk < 2; ++kk) {
      f16x8 af[2], bf[4];
#pragma unroll
      for (int t = 0; t < 2; ++t) af[t] = *(const f16x8*)&As[cur][(wm * 32 + t * 16 + l15) * 72 + kk * 32 + quad * 8];
#pragma unroll
      for (int t = 0; t < 4; ++t) bf[t] = *(const f16x8*)&Bs[cur][(wn * 64 + t * 16 + l15) * 72 + kk * 32 + quad * 8];
      __builtin_amdgcn_s_setprio(1);
#pragma unroll
      for (int i = 0; i < 2; ++i)
#pragma unroll
        for (int j = 0; j < 4; ++j)
          acc[i][j] = MFMA_16x16x32(af[i], bf[j], acc[i][j]);
      __builtin_amdgcn_s_setprio(0);
    }
    if (kt + 1 < 16) {
#pragma unroll
      for (int i = 0; i < 2; ++i)
        *(f16x8*)&As[cur ^ 1][(srow + 32 * i) * 72 + skc] = ra[i];
#pragma unroll
      for (int i = 0; i < 4; ++i)
        *(f16x8*)&Bs[cur ^ 1][(srow + 32 * i) * 72 + skc] = rb[i];
    }
  }

  const int mbase = m0 + wm * 32 + quad * 4;
  const int nbase = n0 + wn * 64 + l15;
#pragma unroll
  for (int j = 0; j < 4; ++j) {
    int n = nbase + j * 16;
    float bv = bias[n];
#pragma unroll
    for (int i = 0; i < 2; ++i) {
      int mrow = mbase + i * 16;
#pragma unroll
      for (int r = 0; r < 4; ++r)
        out[(size_t)(mrow + r) * kDim + n] = acc[i][j][r] + bv;
    }
  }
}

extern "C" void kernel_launch(void* const* d_in, const int* in_sizes, int n_in,
                              void* d_out, int out_size, void* d_ws, size_t ws_size,
                              hipStream_t stream) {
  (void)in_sizes; (void)n_in; (void)out_size; (void)ws_size;
  const float* X    = (const float*)d_in[0];
  const float* mask = (const float*)d_in[1];
  const float* Wq   = (const float*)d_in[2];
  const float* bq   = (const float*)d_in[3];
  const float* Wk   = (const float*)d_in[4];
  const float* bk   = (const float*)d_in[5];
  const float* Wv   = (const float*)d_in[6];
  const float* bv   = (const float*)d_in[7];
  const float* Wo   = (const float*)d_in[8];
  const float* bo   = (const float*)d_in[9];
  float* out = (float*)d_out;

  char* ws = (char*)d_ws;
  _Float16* Xh   = (_Float16*)(ws);                        // 8 MB
  _Float16* Wqt  = (_Float16*)(ws + ((size_t)8  << 20));   // 2 MB each
  _Float16* Wkt  = (_Float16*)(ws + ((size_t)10 << 20));
  _Float16* Wvt  = (_Float16*)(ws + ((size_t)12 << 20));
  _Float16* Wot  = (_Float16*)(ws + ((size_t)14 << 20));
  _Float16* Qh   = (_Float16*)(ws + ((size_t)16 << 20));   // 8 MB each
  _Float16* Kh   = (_Float16*)(ws + ((size_t)24 << 20));
  _Float16* Vh   = (_Float16*)(ws + ((size_t)32 << 20));   // [B][H][D][S]
  _Float16* Ch   = (_Float16*)(ws + ((size_t)40 << 20));   // 8 MB

  cvt_f32_to_f16<<<dim3(kM * kDim / 8 / 256), dim3(256), 0, stream>>>(X, Xh, kM * kDim / 8);
  transpose_cvt_w<<<dim3(16, 16, 4), dim3(256), 0, stream>>>(Wq, Wk, Wv, Wo, Wqt, Wkt, Wvt, Wot);
  gemm_qkv<<<dim3(32, 8, 3), dim3(256), 0, stream>>>(Xh, Wqt, Wkt, Wvt, bq, bk, bv, Qh, Kh, Vh);
  attn<<<dim3(512), dim3(256), 0, stream>>>(Qh, Kh, Vh, mask, Ch);
  gemm_out<<<dim3(64, 8), dim3(256), 0, stream>>>(Ch, Wot, bo, out);
}